// Round 11
// baseline (150.948 us; speedup 1.0000x reference)
//
#include <hip/hip_runtime.h>
#include <stdint.h>
#include <math.h>

// HashingDiscretizer — R16: leaf gathers via sc0 (L1-bypass) inline asm,
// all 8 loads of the 4-elem chunk issued in one block, one vmcnt(0).
//
// Ten-round invariant: R5/R13/R14 all pay ~1 scattered 128B L1 line-fill
// per calibrated element and all land at 57-62us. Measured fill rate
// ~0.12/cy/CU == classic L1 MSHR cap (~24 misses x ~180cy L2 latency).
// Explains: R13 occupancy-doubling null (cap is per-CU, not per-wave),
// R9 batching null (misses queue at L1 regardless), R14's small gain
// (removed L1 HITS only). Fix: sc0 loads bypass L0/L1 entirely and are
// served by the XCD L2's deeper queue. Compiler never emits sc0 on
// loads -> inline asm; loads + s_waitcnt in the SAME asm block (no
// hoisting hazard). Uncal lanes -> offset 0 (wave-uniform line, TA-
// coalesced to 1 request) so request count stays ~= R14.
//
// Structure otherwise = R15: 8-ary bf16-ceil LDS header -> one 32B fp32
// leaf window; bump-repair (rare, plain cached loads) for header
// underestimates; scal sentinel for high keys; generic fallback for
// out-of-range keys. Poison 0xAA reads as uncalibrated; no clear pass.
// Named scalars only (runtime-indexed arrays -> scratch, R6-R8 lesson).

#define GOLDEN   0x9E3779B9u
#define OUT_MASK ((1u << 22) - 1u)
#define NBIN  63
#define NPIV  8192
#define NKEY  16384

typedef float fx4 __attribute__((ext_vector_type(4)));
typedef int   ix4 __attribute__((ext_vector_type(4)));
typedef unsigned ux4 __attribute__((ext_vector_type(4)));

// bf16 ceil (round toward +inf), -0 canonicalized to +0.
__device__ __forceinline__ unsigned bf16c(float x) {
    const unsigned b = __float_as_uint(x);
    unsigned t = ((int)b >= 0) ? ((b + 0xFFFFu) >> 16) : (b >> 16);
    return (t == 0x8000u) ? 0u : t;
}

// ---------------- build (no atomics, no clear) ----------------
__global__ __launch_bounds__(256) void build_tables_kernel(
    const int* __restrict__ fids, const float* __restrict__ bins,
    float* __restrict__ qtab, ux4* __restrict__ spiv16_g,
    unsigned char* __restrict__ scal_g, int F)
{
    const int t = blockIdx.x * blockDim.x + threadIdx.x;
    if (t >= F * 64) return;
    const int r = t >> 6;
    const int j = t & 63;
    const unsigned uk = (unsigned)fids[r];
    const float* src = bins + (size_t)r * NBIN;

    if (uk < (unsigned)NPIV) {
        qtab[((size_t)uk << 6) + j] = (j < NBIN) ? src[j] : INFINITY;
        if (j == 0) {
            const unsigned p0 = bf16c(src[7]),  p1 = bf16c(src[15]),
                           p2 = bf16c(src[23]), p3 = bf16c(src[31]),
                           p4 = bf16c(src[39]), p5 = bf16c(src[47]),
                           p6 = bf16c(src[55]);
            const unsigned tag = 0x6000u | uk;        // uk < 8192
            ux4 q;
            q.x = p0 | (p1 << 16);
            q.y = p2 | (p3 << 16);
            q.z = p4 | (p5 << 16);
            q.w = p6 | (tag << 16);
            spiv16_g[uk] = q;
        }
    } else if (uk < (unsigned)NKEY && j == 0) {
        scal_g[uk - NPIV] = (unsigned char)(0x40u | (uk & 63u));
    }
}

// ---------------- generic fallback ----------------
__device__ __forceinline__ void hd_fallback(
    int k, float v, const int* __restrict__ fids, const float* __restrict__ bins,
    int F, int fsteps, float& okey, float& oval)
{
    int lo = 0, hi = F;
    for (int s = 0; s < fsteps; ++s) {
        int  mid  = (lo + hi) >> 1;
        int  mids = min(mid, F - 1);
        int  fv   = fids[mids];
        bool valid = lo < hi;
        bool right = valid && (fv < k);
        lo = right ? mid + 1 : lo;
        hi = (valid && !right) ? mid : hi;
    }
    const int  idx_safe   = min(lo, F - 1);
    const bool calibrated = (fids[idx_safe] == k);
    const float* brow = bins + (size_t)idx_safe * NBIN;
    int blo = 0, bhi = NBIN;
    #pragma unroll
    for (int s = 0; s < 6; ++s) {
        int   mid  = (blo + bhi) >> 1;
        int   mids = min(mid, NBIN - 1);
        float bv   = brow[mids];
        bool  valid = blo < bhi;
        bool  right = valid && (bv < v);
        blo = right ? mid + 1 : blo;
        bhi = (valid && !right) ? mid : bhi;
    }
    const uint32_t h = ((uint32_t)k * GOLDEN + (uint32_t)blo) * GOLDEN;
    okey = calibrated ? (float)(h & OUT_MASK) : (float)((uint32_t)k & OUT_MASK);
    oval = calibrated ? 1.0f : v;
}

__device__ __forceinline__ int hd_cmp8(fx4 a, fx4 b, float v) {
    return (a.x < v) + (a.y < v) + (a.z < v) + (a.w < v)
         + (b.x < v) + (b.y < v) + (b.z < v) + (b.w < v);
}

// Rare bump path (header underestimated the window): plain cached loads.
__device__ __forceinline__ int hd_leaf_bin_from(const char* qb, unsigned u,
                                                float v, int t)
{
    for (;;) {
        const char* p = qb + ((u << 8) + (unsigned)(t << 5));
        const fx4 a = *reinterpret_cast<const fx4*>(p);
        const fx4 b = *reinterpret_cast<const fx4*>(p + 16);
        const int cnt = hd_cmp8(a, b, v);
        if (cnt == 8 && t < 7) { ++t; continue; }
        return (t << 3) + cnt;
    }
}

// ---------------- main ----------------
__global__ __launch_bounds__(1024, 4) void hd_main_kernel(
    const int* __restrict__ keys, const float* __restrict__ vals,
    const int* __restrict__ fids, const float* __restrict__ bins,
    const float* __restrict__ qtab, const ux4* __restrict__ spiv16_g,
    const unsigned char* __restrict__ scal_g,
    float* __restrict__ out_keys, float* __restrict__ out_vals,
    int n, int F, int fsteps, int nchunks)
{
    extern __shared__ char smem[];
    ux4*      spiv16 = reinterpret_cast<ux4*>(smem);             // 8192 x 16B
    unsigned* scal   = reinterpret_cast<unsigned*>(smem + (size_t)NPIV * 16);

    const int tid = threadIdx.x;
    for (int i = tid; i < NPIV; i += (int)blockDim.x) spiv16[i] = spiv16_g[i];
    const unsigned* scal_g32 = reinterpret_cast<const unsigned*>(scal_g);
    for (int i = tid; i < NPIV / 4; i += (int)blockDim.x) scal[i] = scal_g32[i];
    __syncthreads();

    const unsigned char* scal_b = reinterpret_cast<const unsigned char*>(scal);
    const char* qb = reinterpret_cast<const char*>(qtab);
    const int nthreads = (int)(gridDim.x * blockDim.x);

    for (int c = blockIdx.x * blockDim.x + tid; c < nchunks; c += nthreads) {
        const int i0 = c * 4;
        int   k0, k1, k2, k3;
        float v0, v1, v2, v3;
        const bool full = (i0 + 3 < n);
        if (full) {
            const ix4 ka = *reinterpret_cast<const ix4*>(keys + i0);
            const fx4 va = *reinterpret_cast<const fx4*>(vals + i0);
            k0 = ka.x; k1 = ka.y; k2 = ka.z; k3 = ka.w;
            v0 = va.x; v1 = va.y; v2 = va.z; v3 = va.w;
        } else {
            k0 = keys[min(i0 + 0, n - 1)]; v0 = vals[min(i0 + 0, n - 1)];
            k1 = keys[min(i0 + 1, n - 1)]; v1 = vals[min(i0 + 1, n - 1)];
            k2 = keys[min(i0 + 2, n - 1)]; v2 = vals[min(i0 + 2, n - 1)];
            k3 = keys[min(i0 + 3, n - 1)]; v3 = vals[min(i0 + 3, n - 1)];
        }

        const unsigned u0 = (unsigned)k0, u1 = (unsigned)k1,
                       u2 = (unsigned)k2, u3 = (unsigned)k3;

        // ---- P1: 4 LDS headers (ds_read_b128), back-to-back ----
        const ux4 h0 = spiv16[u0 < (unsigned)NPIV ? u0 : 0u];
        const ux4 h1 = spiv16[u1 < (unsigned)NPIV ? u1 : 0u];
        const ux4 h2 = spiv16[u2 < (unsigned)NPIV ? u2 : 0u];
        const ux4 h3 = spiv16[u3 < (unsigned)NPIV ? u3 : 0u];

        // ---- P2: classify + 8-ary bf16 window (sound underestimate) ----
#define HD_BF(B) __uint_as_float((B) << 16)
#define HD_P2(J)                                                              \
        const bool cal##J = (u##J < (unsigned)NPIV) &&                        \
                            ((h##J.w >> 16) == (0x6000u | u##J));             \
        const int t##J = (HD_BF(h##J.x & 0xFFFFu) < v##J)                     \
                       + (HD_BF(h##J.x >> 16)     < v##J)                     \
                       + (HD_BF(h##J.y & 0xFFFFu) < v##J)                     \
                       + (HD_BF(h##J.y >> 16)     < v##J)                     \
                       + (HD_BF(h##J.z & 0xFFFFu) < v##J)                     \
                       + (HD_BF(h##J.z >> 16)     < v##J)                     \
                       + (HD_BF(h##J.w & 0xFFFFu) < v##J);                    \
        const unsigned hs##J = u##J - (unsigned)NPIV;                         \
        const bool rare##J =                                                  \
            (u##J >= (unsigned)NKEY) ||                                       \
            ((hs##J < (unsigned)NPIV) &&                                      \
             (scal_b[hs##J < (unsigned)NPIV ? hs##J : 0u] ==                  \
              (unsigned char)(0x40u | (u##J & 63u))));
        HD_P2(0) HD_P2(1) HD_P2(2) HD_P2(3)
#undef HD_P2
#undef HD_BF

        // ---- P3: batched sc0 (L1-bypass) leaf gathers, one vmcnt ----
        // Uncal lanes use offset 0 -> wave-uniform line -> TA-coalesced.
        const unsigned off0 = cal0 ? ((u0 << 8) + ((unsigned)t0 << 5)) : 0u;
        const unsigned off1 = cal1 ? ((u1 << 8) + ((unsigned)t1 << 5)) : 0u;
        const unsigned off2 = cal2 ? ((u2 << 8) + ((unsigned)t2 << 5)) : 0u;
        const unsigned off3 = cal3 ? ((u3 << 8) + ((unsigned)t3 << 5)) : 0u;
        const char* p0 = qb + off0;
        const char* p1 = qb + off1;
        const char* p2 = qb + off2;
        const char* p3 = qb + off3;
        fx4 a0, b0, a1, b1, a2, b2, a3, b3;
        asm volatile(
            "global_load_dwordx4 %0, %8, off sc0\n\t"
            "global_load_dwordx4 %1, %8, off offset:16 sc0\n\t"
            "global_load_dwordx4 %2, %9, off sc0\n\t"
            "global_load_dwordx4 %3, %9, off offset:16 sc0\n\t"
            "global_load_dwordx4 %4, %10, off sc0\n\t"
            "global_load_dwordx4 %5, %10, off offset:16 sc0\n\t"
            "global_load_dwordx4 %6, %11, off sc0\n\t"
            "global_load_dwordx4 %7, %11, off offset:16 sc0\n\t"
            "s_waitcnt vmcnt(0)"
            : "=&v"(a0), "=&v"(b0), "=&v"(a1), "=&v"(b1),
              "=&v"(a2), "=&v"(b2), "=&v"(a3), "=&v"(b3)
            : "v"(p0), "v"(p1), "v"(p2), "v"(p3)
            : "memory");

        // ---- P4: count + rare bump repair + hash + branchless select ----
        float ok0, ok1, ok2, ok3, ov0, ov1, ov2, ov3;
#define HD_P4(J)                                                              \
        {                                                                     \
            const int cnt = hd_cmp8(a##J, b##J, v##J);                        \
            int bin;                                                          \
            if (__builtin_expect(cal##J && cnt == 8 && t##J < 7, 0))          \
                bin = hd_leaf_bin_from(qb, u##J, v##J, t##J + 1);             \
            else                                                              \
                bin = (t##J << 3) + cnt;                                      \
            const uint32_t h = (u##J * GOLDEN + (uint32_t)bin) * GOLDEN;      \
            ok##J = cal##J ? (float)(h & OUT_MASK) : (float)(u##J & OUT_MASK);\
            ov##J = cal##J ? 1.0f : v##J;                                     \
        }
        HD_P4(0) HD_P4(1) HD_P4(2) HD_P4(3)
#undef HD_P4

        // ---- cold path (absent in bench data) ----
        if (__builtin_expect(rare0 | rare1 | rare2 | rare3, 0)) {
            if (rare0) hd_fallback(k0, v0, fids, bins, F, fsteps, ok0, ov0);
            if (rare1) hd_fallback(k1, v1, fids, bins, F, fsteps, ok1, ov1);
            if (rare2) hd_fallback(k2, v2, fids, bins, F, fsteps, ok2, ov2);
            if (rare3) hd_fallback(k3, v3, fids, bins, F, fsteps, ok3, ov3);
        }

        if (full) {
            fx4 s;
            s.x = ok0; s.y = ok1; s.z = ok2; s.w = ok3;
            __builtin_nontemporal_store(s, reinterpret_cast<fx4*>(out_keys + i0));
            s.x = ov0; s.y = ov1; s.z = ov2; s.w = ov3;
            __builtin_nontemporal_store(s, reinterpret_cast<fx4*>(out_vals + i0));
        } else {
            if (i0 + 0 < n) { out_keys[i0 + 0] = ok0; out_vals[i0 + 0] = ov0; }
            if (i0 + 1 < n) { out_keys[i0 + 1] = ok1; out_vals[i0 + 1] = ov1; }
            if (i0 + 2 < n) { out_keys[i0 + 2] = ok2; out_vals[i0 + 2] = ov2; }
            if (i0 + 3 < n) { out_keys[i0 + 3] = ok3; out_vals[i0 + 3] = ov3; }
        }
    }
}

// Pure binary-search kernel: used only if LDS or workspace is insufficient.
__global__ __launch_bounds__(256) void hd_simple_kernel(
    const int* __restrict__ keys, const float* __restrict__ vals,
    const int* __restrict__ fids, const float* __restrict__ bins,
    float* __restrict__ out_keys, float* __restrict__ out_vals,
    int n, int F, int fsteps)
{
    const int gid = blockIdx.x * blockDim.x + threadIdx.x;
    const int i0 = gid * 4;
    if (i0 >= n) return;
    #pragma unroll
    for (int j = 0; j < 4; ++j) {
        int idx = min(i0 + j, n - 1);
        float okey, oval;
        hd_fallback(keys[idx], vals[idx], fids, bins, F, fsteps, okey, oval);
        if (i0 + j < n) { out_keys[i0 + j] = okey; out_vals[i0 + j] = oval; }
    }
}

extern "C" void kernel_launch(void* const* d_in, const int* in_sizes, int n_in,
                              void* d_out, int out_size, void* d_ws, size_t ws_size,
                              hipStream_t stream) {
    const int*   keys = (const int*)d_in[0];
    const float* vals = (const float*)d_in[1];
    const int*   fids = (const int*)d_in[2];
    const float* bins = (const float*)d_in[3];

    const int n = in_sizes[0];
    const int F = in_sizes[2];

    int fsteps = 0;
    while ((1 << fsteps) < F + 1) ++fsteps;

    float* out_keys = (float*)d_out;
    float* out_vals = (float*)d_out + n;

    // ws: qtab (2 MB) | spiv16 (128 KB) | scal (8 KB)
    const size_t qtab_bytes = (size_t)NPIV * 64 * sizeof(float);
    const size_t spiv_bytes = (size_t)NPIV * 16;
    const size_t scal_bytes = (size_t)NPIV;
    const size_t ws_need    = qtab_bytes + spiv_bytes + scal_bytes;
    const size_t lds_bytes  = spiv_bytes + scal_bytes;   // 139264 B

    int max_lds = 0;
    hipDeviceGetAttribute(&max_lds, hipDeviceAttributeMaxSharedMemoryPerBlock, 0);

    const bool fast = (ws_size >= ws_need) && ((size_t)max_lds >= lds_bytes) &&
                      (in_sizes[3] == F * NBIN) && (F <= NPIV);

    if (fast) {
        float*         qtab     = (float*)d_ws;
        ux4*           spiv16_g = (ux4*)((char*)d_ws + qtab_bytes);
        unsigned char* scal_g   = (unsigned char*)d_ws + qtab_bytes + spiv_bytes;

        build_tables_kernel<<<(F * 64 + 255) / 256, 256, 0, stream>>>(
            fids, bins, qtab, spiv16_g, scal_g, F);

        (void)hipFuncSetAttribute(
            reinterpret_cast<const void*>(hd_main_kernel),
            hipFuncAttributeMaxDynamicSharedMemorySize, (int)lds_bytes);

        const int threads = 1024;
        const int nblocks = 256;           // 1 block/CU; LDS fill once per CU
        const int nchunks = (n + 3) / 4;
        hd_main_kernel<<<nblocks, threads, lds_bytes, stream>>>(
            keys, vals, fids, bins, qtab, spiv16_g, scal_g,
            out_keys, out_vals, n, F, fsteps, nchunks);
    } else {
        const int threads = 256;
        const int grid = (n + threads * 4 - 1) / (threads * 4);
        hd_simple_kernel<<<grid, threads, 0, stream>>>(
            keys, vals, fids, bins, out_keys, out_vals, n, F, fsteps);
    }
}